// Round 4
// baseline (4789.333 us; speedup 1.0000x reference)
//
#include <hip/hip_runtime.h>
#include <hip/hip_bf16.h>
#include <stdint.h>

typedef __bf16 bf16_t;
typedef bf16_t bf16x8 __attribute__((ext_vector_type(8)));
typedef float  f32x4  __attribute__((ext_vector_type(4)));
typedef float  f32x16 __attribute__((ext_vector_type(16)));

#define I_DIM 512
#define H_DIM 1024
#define B_DIM 64
#define S_DIM 512
#define G4    4096   // 4*H
#define CHUNK 32     // xproj steps per chunk == steps per persistent dispatch
#define NCHUNK (S_DIM / CHUNK)

// ---------------- workspace layout (bytes) — total ~34 MB ----------------
#define O_WXT   0x0000000ULL  // [4096][512]  bf16 = 4 MB   (packed WxT, row-major)
#define O_WHTF  0x0400000ULL  // [128][64][64][8] bf16 = 8 MB (Wh in MFMA B-frag order)
#define O_BIAS  0x0C00000ULL  // [4096] f32 = 16 KB
#define O_CST   0x0C10000ULL  // [64][1024] f32 = 256 KB (c-state, chunk-boundary only)
#define O_HBUF  0x0D00000ULL  // 2 slots * 128 KB (h in A-frag order) = 256 KB
#define O_FLG   0x0D40000ULL  // 4 KB: flags[256] u32, flags[bh*128+q] = latest h version
#define O_XP    0x1200000ULL  // [CHUNK*64][4096] bf16 = 16 MB

__device__ __forceinline__ float sigm(float x)      { return 1.f / (1.f + __expf(-x)); }
__device__ __forceinline__ float tanh_fast(float x) { return 1.f - 2.f / (__expf(2.f * x) + 1.f); }

// Packed gate-column permutation: packed col p = q*32 + g*8 + jj  <->  hidden j = q*8+jj, gate g (0:i 1:f 2:g 3:o)

__global__ void k_pack_wx(const float* __restrict__ w0, const float* __restrict__ w1,
                          const float* __restrict__ w2, const float* __restrict__ w3,
                          bf16_t* __restrict__ wxt) {
    int tid = blockIdx.x * 256 + threadIdx.x;
    int k = tid >> 12;
    int p = tid & 4095;
    int q = p >> 5, g = (p >> 3) & 3, jj = p & 7;
    int j = q * 8 + jj;
    const float* src = (g == 0) ? w0 : (g == 1) ? w1 : (g == 2) ? w2 : w3;
    wxt[(size_t)p * I_DIM + k] = (bf16_t)src[k * H_DIM + j];
}

// Wh -> global MFMA B-fragment order: whtf[q][ks][lane][8]
//   element = WhT[p = q*32 + (lane&31)][k = ks*16 + (lane>>5)*8 + e]
__global__ void k_pack_whf(const float* __restrict__ w0, const float* __restrict__ w1,
                           const float* __restrict__ w2, const float* __restrict__ w3,
                           bf16_t* __restrict__ whtf) {
    int idx = blockIdx.x * 256 + threadIdx.x;     // 0..4194303
    int e    = idx & 7;
    int lane = (idx >> 3) & 63;
    int ks   = (idx >> 9) & 63;
    int q    = idx >> 15;                          // 0..127
    int k = ks * 16 + (lane >> 5) * 8 + e;
    int c = lane & 31;
    int g = c >> 3, jj = c & 7;
    int j = q * 8 + jj;
    const float* src = (g == 0) ? w0 : (g == 1) ? w1 : (g == 2) ? w2 : w3;
    whtf[idx] = (bf16_t)src[k * H_DIM + j];
}

__global__ void k_pack_bias(const float* bi0, const float* bh0, const float* bi1, const float* bh1,
                            const float* bi2, const float* bh2, const float* bi3, const float* bh3,
                            float* __restrict__ bias) {
    int p = blockIdx.x * 256 + threadIdx.x;
    int q = p >> 5, g = (p >> 3) & 3, jj = p & 7;
    int j = q * 8 + jj;
    const float* a = (g == 0) ? bi0 : (g == 1) ? bi1 : (g == 2) ? bi2 : bi3;
    const float* b = (g == 0) ? bh0 : (g == 1) ? bh1 : (g == 2) ? bh2 : bh3;
    bias[p] = a[j] + b[j];
}

// ---------------- chunked x_proj GEMM (unchanged) ----------------
__global__ __launch_bounds__(256, 2) void k_xproj(
    const float* __restrict__ x, const bf16_t* __restrict__ wxt,
    const float* __restrict__ bias, bf16_t* __restrict__ xp, int r_base)
{
    __shared__ __align__(16) bf16_t Al[8 * 64 * 8];
    __shared__ __align__(16) bf16_t Bl[8 * 64 * 8];
    const int tid = threadIdx.x;
    const int n0 = blockIdx.x * 128;
    const int r0 = r_base + blockIdx.y * 128;
    const int wv = tid >> 6;
    const int lane = tid & 63;
    const int mq = wv >> 1, nq = wv & 1;
    f32x4 acc[4][4] = {};

    for (int kk = 0; kk < I_DIM; kk += 32) {
        __syncthreads();
        #pragma unroll
        for (int sidx = 0; sidx < 2; ++sidx) {
            int s = tid + sidx * 256;
            int mt = s >> 6, l = s & 63;
            int m = l & 15, kb = (l >> 4) * 8;
            int r = r0 + mt * 16 + m;
            int b = r & 63, si = r >> 6;
            const float* gp = x + ((size_t)(b * S_DIM + si)) * I_DIM + kk + kb;
            float4 v0 = *(const float4*)gp;
            float4 v1 = *(const float4*)(gp + 4);
            bf16x8 a;
            a[0] = (bf16_t)v0.x; a[1] = (bf16_t)v0.y; a[2] = (bf16_t)v0.z; a[3] = (bf16_t)v0.w;
            a[4] = (bf16_t)v1.x; a[5] = (bf16_t)v1.y; a[6] = (bf16_t)v1.z; a[7] = (bf16_t)v1.w;
            *(bf16x8*)&Al[s * 8] = a;
            bf16x8 bv = *(const bf16x8*)(wxt + (size_t)(n0 + mt * 16 + m) * I_DIM + kk + kb);
            *(bf16x8*)&Bl[s * 8] = bv;
        }
        __syncthreads();
        bf16x8 af[4], bfr[4];
        #pragma unroll
        for (int mt = 0; mt < 4; ++mt) af[mt]  = *(bf16x8*)&Al[((mq * 4 + mt) * 64 + lane) * 8];
        #pragma unroll
        for (int nt = 0; nt < 4; ++nt) bfr[nt] = *(bf16x8*)&Bl[((nq * 4 + nt) * 64 + lane) * 8];
        #pragma unroll
        for (int mt = 0; mt < 4; ++mt)
            #pragma unroll
            for (int nt = 0; nt < 4; ++nt)
                acc[mt][nt] = __builtin_amdgcn_mfma_f32_16x16x32_bf16(af[mt], bfr[nt], acc[mt][nt], 0, 0, 0);
    }
    const int l15 = lane & 15, quad = lane >> 4;
    #pragma unroll
    for (int nt = 0; nt < 4; ++nt) {
        int col = n0 + nq * 64 + nt * 16 + l15;
        float bv = bias[col];
        #pragma unroll
        for (int mt = 0; mt < 4; ++mt)
            #pragma unroll
            for (int r = 0; r < 4; ++r) {
                int row = r0 - r_base + mq * 64 + mt * 16 + quad * 4 + r;
                xp[(size_t)row * G4 + col] = (bf16_t)(acc[mt][nt][r] + bv);
            }
    }
}

// ---------------- 32 LSTM time-steps per persistent dispatch ----------------
// R10: flag-gated dataflow on R8's PROVEN primitives. R9's hand-rolled
// sc0/sc1 asm hung (likely stores stuck dirty in producer L2 -> consumers
// spun forever). Rebuild: all cross-WG traffic via __hip_atomic_* AGENT
// relaxed (R8-proven coherent across XCDs), ordering via s_waitcnt vmcnt(0)
// (R8-proven drain-to-coherence-point before its barrier arrival).
// Sync = per-producer flags (monotonic version counters), NOT a barrier:
//   producer: h-slice stores (relaxed agent u64) -> vmcnt(0) -> flag=t+1
//   consumer: poll own half's 128 flags (1 coalesced load/lane tid<128 +
//             __syncthreads_and) until all >= t, THEN load h.
// Serial chain = store-drain + flag-land + one poll observe (~1.5us) vs
// R8's arrive->root->epoch->poll (~3.3us). WG skew absorbed, not synced.
// Slot WAR safety (induction): producer of h_{t+2} passed poll for h_{t+1}
// => every WG of its half set flag t+1 => every WG finished reading h_t.
__global__ __launch_bounds__(256, 1) void k_steps(
    const bf16_t* __restrict__ whtf, const bf16_t* __restrict__ xp_c,
    bf16_t* __restrict__ hbuf, float* __restrict__ cstbuf,
    float* __restrict__ out, uint32_t* __restrict__ flags,
    int t_base, int write_out_last)
{
    __shared__ float Pl[4][16][64];               // partials [wave][reg][lane], 16 KB
    __shared__ __align__(16) bf16_t Hlds[256];    // h staging for the frag-order store
    const int tid  = threadIdx.x;
    const int w    = tid >> 6;                    // K-quarter index
    const int lane = tid & 63;
    const int bid  = blockIdx.x;
    const int q    = bid & 127;                   // packed col-block (32 cols)
    const int bh   = bid >> 7;                    // batch half

    const int col  = lane & 31;
    const int ksel = lane >> 5;
    const int gt   = (lane >> 3) & 3;  // 0:i 1:f 2:g 3:o
    const int jj   = lane & 7;

    int rrow[4];
    #pragma unroll
    for (int e = 0; e < 4; ++e) rrow[e] = e + 8 * w + 4 * ksel;

    // Loop-invariant B fragments: loaded once, live in VGPRs all chunk.
    const bf16_t* bb = whtf + ((size_t)q << 15) + (w << 13) + (lane << 3);
    bf16x8 bfr[16];
    #pragma unroll
    for (int i = 0; i < 16; ++i) bfr[i] = *(const bf16x8*)(bb + i * 512);

    // c-state in registers for the whole chunk (i-gate lanes only).
    float cst[4] = {0.f, 0.f, 0.f, 0.f};
    if (gt == 0) {
        #pragma unroll
        for (int e = 0; e < 4; ++e)
            cst[e] = cstbuf[(bh * 32 + rrow[e]) * H_DIM + q * 8 + jj];
    }

    const int abase = (bh << 15) + (w << 13) + (lane << 3);  // h A-frag base (bf16 elements)

    for (int tl = 0; tl < CHUNK; ++tl) {
        const int gstep = t_base + tl;

        // xp loads first: dispatch-constant data, overlaps the flag poll.
        const bf16_t* xp_t = xp_c + (size_t)(tl * 64) * G4;
        bf16_t xpr[4];
        #pragma unroll
        for (int e = 0; e < 4; ++e)
            xpr[e] = xp_t[(size_t)(bh * 32 + rrow[e]) * G4 + q * 32 + col];

        // Wait until every producer of this batch-half has published h_{gstep}.
        {
            const uint32_t target = (uint32_t)gstep;
            for (;;) {
                int ok = 1;
                if (tid < 128)
                    ok = (__hip_atomic_load(&flags[(bh << 7) + tid], __ATOMIC_RELAXED,
                                            __HIP_MEMORY_SCOPE_AGENT) >= target);
                if (__syncthreads_and(ok)) break;
            }
        }
        asm volatile("" ::: "memory");   // no hoisting of h loads above the poll

        // h loads: 32 relaxed agent u64 (L2-bypassing, coherent at L3).
        const uint64_t* hsrc = (const uint64_t*)(hbuf + ((gstep & 1) << 16) + abase);
        uint64_t hl0[16], hl1[16];
        #pragma unroll
        for (int i = 0; i < 16; ++i) {
            hl0[i] = __hip_atomic_load(hsrc + i * 128,     __ATOMIC_RELAXED, __HIP_MEMORY_SCOPE_AGENT);
            hl1[i] = __hip_atomic_load(hsrc + i * 128 + 1, __ATOMIC_RELAXED, __HIP_MEMORY_SCOPE_AGENT);
        }

        struct U2 { uint64_t a, b; };
        f32x16 acc0 = {}, acc1 = {}, acc2 = {}, acc3 = {};
        #pragma unroll
        for (int i = 0; i < 16; i += 4) {
            U2 t0{hl0[i + 0], hl1[i + 0]};
            U2 t1{hl0[i + 1], hl1[i + 1]};
            U2 t2{hl0[i + 2], hl1[i + 2]};
            U2 t3{hl0[i + 3], hl1[i + 3]};
            acc0 = __builtin_amdgcn_mfma_f32_32x32x16_bf16(__builtin_bit_cast(bf16x8, t0), bfr[i + 0], acc0, 0, 0, 0);
            acc1 = __builtin_amdgcn_mfma_f32_32x32x16_bf16(__builtin_bit_cast(bf16x8, t1), bfr[i + 1], acc1, 0, 0, 0);
            acc2 = __builtin_amdgcn_mfma_f32_32x32x16_bf16(__builtin_bit_cast(bf16x8, t2), bfr[i + 2], acc2, 0, 0, 0);
            acc3 = __builtin_amdgcn_mfma_f32_32x32x16_bf16(__builtin_bit_cast(bf16x8, t3), bfr[i + 3], acc3, 0, 0, 0);
        }
        f32x16 accs = acc0 + acc1 + acc2 + acc3;

        #pragma unroll
        for (int e = 0; e < 16; ++e) Pl[w][e][lane] = accs[e];
        __syncthreads();

        #pragma unroll
        for (int e = 0; e < 4; ++e) {
            int eg = w * 4 + e;
            float pre = Pl[0][eg][lane] + Pl[1][eg][lane] + Pl[2][eg][lane] + Pl[3][eg][lane];
            pre += (float)xpr[e];
            float a = (gt == 2) ? tanh_fast(pre) : sigm(pre);

            float fv = __shfl_xor(a, 8, 64);
            float gv = __shfl_xor(a, 16, 64);
            float ov = __shfl_xor(a, 24, 64);
            if (gt == 0) {
                float cn = fv * cst[e] + a * gv;
                float hv = ov * tanh_fast(cn);
                cst[e] = cn;
                Hlds[rrow[e] * 8 + jj] = (bf16_t)hv;
                if (write_out_last && tl == CHUNK - 1) {
                    int rowg = bh * 32 + rrow[e];
                    int j = q * 8 + jj;
                    out[rowg * H_DIM + j] = hv;            // h_T
                    out[65536 + rowg * H_DIM + j] = cn;    // c_T
                }
            }
        }
        __syncthreads();   // Hlds complete; also fences Pl reuse next step

        // Publish this WG's h slice, then its flag. Flag only after the h
        // stores have drained to the coherence point (vmcnt(0), R8-proven).
        if (w == 0) {
            uint64_t v = *(const uint64_t*)&Hlds[lane * 4];
            uint64_t* hdst = (uint64_t*)hbuf + (((gstep + 1) & 1) << 14)
                           + (bh << 13) + (q << 6) + lane;
            __hip_atomic_store(hdst, v, __ATOMIC_RELAXED, __HIP_MEMORY_SCOPE_AGENT);
            asm volatile("s_waitcnt vmcnt(0)" ::: "memory");
            if (lane == 0)
                __hip_atomic_store(&flags[(bh << 7) + q], (uint32_t)(gstep + 1),
                                   __ATOMIC_RELAXED, __HIP_MEMORY_SCOPE_AGENT);
        }
    }

    // c-state writeback for the next chunk (normal stores; dispatch-end release)
    if (gt == 0) {
        #pragma unroll
        for (int e = 0; e < 4; ++e)
            cstbuf[(bh * 32 + rrow[e]) * H_DIM + q * 8 + jj] = cst[e];
    }
}

extern "C" void kernel_launch(void* const* d_in, const int* in_sizes, int n_in,
                              void* d_out, int out_size, void* d_ws, size_t ws_size,
                              hipStream_t stream) {
    const float* x   = (const float*)d_in[0];
    const float* wii = (const float*)d_in[1];
    const float* bii = (const float*)d_in[2];
    const float* whi = (const float*)d_in[3];
    const float* bhi = (const float*)d_in[4];
    const float* wif = (const float*)d_in[5];
    const float* bif = (const float*)d_in[6];
    const float* whf = (const float*)d_in[7];
    const float* bhf = (const float*)d_in[8];
    const float* wig = (const float*)d_in[9];
    const float* big = (const float*)d_in[10];
    const float* whg = (const float*)d_in[11];
    const float* bhg = (const float*)d_in[12];
    const float* wio = (const float*)d_in[13];
    const float* bio = (const float*)d_in[14];
    const float* who = (const float*)d_in[15];
    const float* bho = (const float*)d_in[16];

    char* ws = (char*)d_ws;
    bf16_t*   wxt  = (bf16_t*)(ws + O_WXT);
    bf16_t*   whtf = (bf16_t*)(ws + O_WHTF);
    float*    bias = (float*)(ws + O_BIAS);
    float*    cstb = (float*)(ws + O_CST);
    bf16_t*   hbuf = (bf16_t*)(ws + O_HBUF);
    uint32_t* flg  = (uint32_t*)(ws + O_FLG);
    bf16_t*   xp   = (bf16_t*)(ws + O_XP);

    hipMemsetAsync(hbuf, 0, 256 * 1024, stream);   // both h slots = 0
    hipMemsetAsync(cstb, 0, 256 * 1024, stream);   // c0 = 0
    hipMemsetAsync(flg,  0, 4096, stream);         // flags = 0 (reset each replay)

    k_pack_wx<<<8192, 256, 0, stream>>>(wii, wif, wig, wio, wxt);
    k_pack_whf<<<16384, 256, 0, stream>>>(whi, whf, whg, who, whtf);
    k_pack_bias<<<16, 256, 0, stream>>>(bii, bhi, bif, bhf, big, bhg, bio, bho, bias);

    float* out = (float*)d_out;
    for (int c = 0; c < NCHUNK; ++c) {
        k_xproj<<<dim3(32, CHUNK * 64 / 128), 256, 0, stream>>>(x, wxt, bias, xp, c * CHUNK * 64);
        int t_base = c * CHUNK;
        int wol    = (c == NCHUNK - 1) ? 1 : 0;
        void* args[] = { (void*)&whtf, (void*)&xp, (void*)&hbuf, (void*)&cstb,
                         (void*)&out, (void*)&flg, (void*)&t_base, (void*)&wol };
        hipError_t err = hipLaunchCooperativeKernel((const void*)k_steps, dim3(256), dim3(256),
                                                    args, 0, stream);
        if (err != hipSuccess) {
            k_steps<<<256, 256, 0, stream>>>(whtf, xp, hbuf, cstb, out, flg, t_base, wol);
        }
    }
}

// Round 5
// 4565.957 us; speedup vs baseline: 1.0489x; 1.0489x over previous
//
#include <hip/hip_runtime.h>
#include <hip/hip_bf16.h>
#include <stdint.h>

typedef __bf16 bf16_t;
typedef bf16_t bf16x8 __attribute__((ext_vector_type(8)));
typedef float  f32x4  __attribute__((ext_vector_type(4)));
typedef float  f32x16 __attribute__((ext_vector_type(16)));

#define I_DIM 512
#define H_DIM 1024
#define B_DIM 64
#define S_DIM 512
#define G4    4096   // 4*H
#define CHUNK 16     // steps per fused dispatch (halved so xp double-buffers fit)
#define NCHUNK (S_DIM / CHUNK)
#define XPSLOT_ELEMS ((size_t)CHUNK * 64 * G4)   // 1024*4096 bf16 = 8 MB

// ---------------- workspace layout (bytes) — total ~34 MB ----------------
#define O_WXT   0x0000000ULL  // [4096][512]  bf16 = 4 MB   (packed WxT, row-major)
#define O_WHTF  0x0400000ULL  // [128][64][64][8] bf16 = 8 MB (Wh in MFMA B-frag order)
#define O_BIAS  0x0C00000ULL  // [4096] f32 = 16 KB
#define O_CST   0x0C10000ULL  // [64][1024] f32 = 256 KB (c-state, chunk-boundary only)
#define O_HBUF  0x0D00000ULL  // 2 slots * 128 KB (h in A-frag order) = 256 KB
#define O_FLG   0x0D40000ULL  // 4 KB: flags[256] u32, flags[bh*128+q] = latest h version
#define O_XP    0x1200000ULL  // 2 slots * [1024][4096] bf16 = 16 MB

__device__ __forceinline__ float sigm(float x)      { return 1.f / (1.f + __expf(-x)); }
__device__ __forceinline__ float tanh_fast(float x) { return 1.f - 2.f / (__expf(2.f * x) + 1.f); }

// Packed gate-column permutation: packed col p = q*32 + g*8 + jj  <->  hidden j = q*8+jj, gate g (0:i 1:f 2:g 3:o)

__global__ void k_pack_wx(const float* __restrict__ w0, const float* __restrict__ w1,
                          const float* __restrict__ w2, const float* __restrict__ w3,
                          bf16_t* __restrict__ wxt) {
    int tid = blockIdx.x * 256 + threadIdx.x;
    int k = tid >> 12;
    int p = tid & 4095;
    int q = p >> 5, g = (p >> 3) & 3, jj = p & 7;
    int j = q * 8 + jj;
    const float* src = (g == 0) ? w0 : (g == 1) ? w1 : (g == 2) ? w2 : w3;
    wxt[(size_t)p * I_DIM + k] = (bf16_t)src[k * H_DIM + j];
}

// Wh -> global MFMA B-fragment order: whtf[q][ks][lane][8]
//   element = WhT[p = q*32 + (lane&31)][k = ks*16 + (lane>>5)*8 + e]
__global__ void k_pack_whf(const float* __restrict__ w0, const float* __restrict__ w1,
                           const float* __restrict__ w2, const float* __restrict__ w3,
                           bf16_t* __restrict__ whtf) {
    int idx = blockIdx.x * 256 + threadIdx.x;     // 0..4194303
    int e    = idx & 7;
    int lane = (idx >> 3) & 63;
    int ks   = (idx >> 9) & 63;
    int q    = idx >> 15;                          // 0..127
    int k = ks * 16 + (lane >> 5) * 8 + e;
    int c = lane & 31;
    int g = c >> 3, jj = c & 7;
    int j = q * 8 + jj;
    const float* src = (g == 0) ? w0 : (g == 1) ? w1 : (g == 2) ? w2 : w3;
    whtf[idx] = (bf16_t)src[k * H_DIM + j];
}

__global__ void k_pack_bias(const float* bi0, const float* bh0, const float* bi1, const float* bh1,
                            const float* bi2, const float* bh2, const float* bi3, const float* bh3,
                            float* __restrict__ bias) {
    int p = blockIdx.x * 256 + threadIdx.x;
    int q = p >> 5, g = (p >> 3) & 3, jj = p & 7;
    int j = q * 8 + jj;
    const float* a = (g == 0) ? bi0 : (g == 1) ? bi1 : (g == 2) ? bi2 : bi3;
    const float* b = (g == 0) ? bh0 : (g == 1) ? bh1 : (g == 2) ? bh2 : bh3;
    bias[p] = a[j] + b[j];
}

// ---------------- standalone x_proj GEMM (chunk 0 only) ----------------
__global__ __launch_bounds__(256, 2) void k_xproj(
    const float* __restrict__ x, const bf16_t* __restrict__ wxt,
    const float* __restrict__ bias, bf16_t* __restrict__ xp, int r_base)
{
    __shared__ __align__(16) bf16_t Al[8 * 64 * 8];
    __shared__ __align__(16) bf16_t Bl[8 * 64 * 8];
    const int tid = threadIdx.x;
    const int n0 = blockIdx.x * 128;
    const int r0 = r_base + blockIdx.y * 128;
    const int wv = tid >> 6;
    const int lane = tid & 63;
    const int mq = wv >> 1, nq = wv & 1;
    f32x4 acc[4][4] = {};

    for (int kk = 0; kk < I_DIM; kk += 32) {
        __syncthreads();
        #pragma unroll
        for (int sidx = 0; sidx < 2; ++sidx) {
            int s = tid + sidx * 256;
            int mt = s >> 6, l = s & 63;
            int m = l & 15, kb = (l >> 4) * 8;
            int r = r0 + mt * 16 + m;
            int b = r & 63, si = r >> 6;
            const float* gp = x + ((size_t)(b * S_DIM + si)) * I_DIM + kk + kb;
            float4 v0 = *(const float4*)gp;
            float4 v1 = *(const float4*)(gp + 4);
            bf16x8 a;
            a[0] = (bf16_t)v0.x; a[1] = (bf16_t)v0.y; a[2] = (bf16_t)v0.z; a[3] = (bf16_t)v0.w;
            a[4] = (bf16_t)v1.x; a[5] = (bf16_t)v1.y; a[6] = (bf16_t)v1.z; a[7] = (bf16_t)v1.w;
            *(bf16x8*)&Al[s * 8] = a;
            bf16x8 bv = *(const bf16x8*)(wxt + (size_t)(n0 + mt * 16 + m) * I_DIM + kk + kb);
            *(bf16x8*)&Bl[s * 8] = bv;
        }
        __syncthreads();
        bf16x8 af[4], bfr[4];
        #pragma unroll
        for (int mt = 0; mt < 4; ++mt) af[mt]  = *(bf16x8*)&Al[((mq * 4 + mt) * 64 + lane) * 8];
        #pragma unroll
        for (int nt = 0; nt < 4; ++nt) bfr[nt] = *(bf16x8*)&Bl[((nq * 4 + nt) * 64 + lane) * 8];
        #pragma unroll
        for (int mt = 0; mt < 4; ++mt)
            #pragma unroll
            for (int nt = 0; nt < 4; ++nt)
                acc[mt][nt] = __builtin_amdgcn_mfma_f32_16x16x32_bf16(af[mt], bfr[nt], acc[mt][nt], 0, 0, 0);
    }
    const int l15 = lane & 15, quad = lane >> 4;
    #pragma unroll
    for (int nt = 0; nt < 4; ++nt) {
        int col = n0 + nq * 64 + nt * 16 + l15;
        float bv = bias[col];
        #pragma unroll
        for (int mt = 0; mt < 4; ++mt)
            #pragma unroll
            for (int r = 0; r < 4; ++r) {
                int row = r0 - r_base + mq * 64 + mt * 16 + quad * 4 + r;
                xp[(size_t)row * G4 + col] = (bf16_t)(acc[mt][nt][r] + bv);
            }
    }
}

// ---------------- fused dispatch: 16 steps + next chunk's xproj ----------------
// R11. Blocks 0..255: flag-gated LSTM steps (R10 machinery, fixed poll).
// Blocks 256..511: xproj for chunk c+1 into the other xp slot (plain
// stores; read next dispatch across the boundary = coherent).
// R10 post-mortem: 8.3us/step came from the poll loop itself — 128-lane
// agent loads + __syncthreads_and PER ITERATION (~1.3us/iter, serialized).
// Fix: wave 0 only, 2 flags/lane, tight __all loop, no block sync inside;
// one __syncthreads releases the other 3 waves. Producer side unchanged
// (h stores -> vmcnt(0) -> flag store, all AGENT scope, R10-proven).
// Co-residency: 512 blocks x 256 thr, VGPR<=128, LDS ~25KB -> 2 blocks/CU
// on 256 CUs regardless of dispatch order; xproj blocks have no sync deps.
__global__ __launch_bounds__(256, 2) void k_fused(
    const float* __restrict__ x, const bf16_t* __restrict__ wxt,
    const float* __restrict__ bias, const bf16_t* __restrict__ whtf,
    const bf16_t* __restrict__ xp_rd, bf16_t* __restrict__ xp_wr,
    bf16_t* __restrict__ hbuf, float* __restrict__ cstbuf,
    float* __restrict__ out, uint32_t* __restrict__ flags,
    int t_base, int write_out_last, int next_r_base, int has_next)
{
    __shared__ float Pl[4][16][64];               // step: partials, 16 KB
    __shared__ __align__(16) bf16_t Hlds[256];    // step: h staging
    __shared__ __align__(16) bf16_t Al[8 * 64 * 8];  // xproj: A tile, 4 KB
    __shared__ __align__(16) bf16_t Bl[8 * 64 * 8];  // xproj: B tile, 4 KB
    const int tid  = threadIdx.x;

    if (blockIdx.x >= 256) {
        // ---------------- xproj path (next chunk) ----------------
        if (!has_next) return;
        const int xbid = blockIdx.x - 256;
        const int n0 = (xbid & 31) * 128;
        const int r0 = next_r_base + (xbid >> 5) * 128;
        const int wv = tid >> 6;
        const int lane = tid & 63;
        const int mq = wv >> 1, nq = wv & 1;
        f32x4 acc[4][4] = {};

        for (int kk = 0; kk < I_DIM; kk += 32) {
            __syncthreads();
            #pragma unroll
            for (int sidx = 0; sidx < 2; ++sidx) {
                int s = tid + sidx * 256;
                int mt = s >> 6, l = s & 63;
                int m = l & 15, kb = (l >> 4) * 8;
                int r = r0 + mt * 16 + m;
                int b = r & 63, si = r >> 6;
                const float* gp = x + ((size_t)(b * S_DIM + si)) * I_DIM + kk + kb;
                float4 v0 = *(const float4*)gp;
                float4 v1 = *(const float4*)(gp + 4);
                bf16x8 a;
                a[0] = (bf16_t)v0.x; a[1] = (bf16_t)v0.y; a[2] = (bf16_t)v0.z; a[3] = (bf16_t)v0.w;
                a[4] = (bf16_t)v1.x; a[5] = (bf16_t)v1.y; a[6] = (bf16_t)v1.z; a[7] = (bf16_t)v1.w;
                *(bf16x8*)&Al[s * 8] = a;
                bf16x8 bv = *(const bf16x8*)(wxt + (size_t)(n0 + mt * 16 + m) * I_DIM + kk + kb);
                *(bf16x8*)&Bl[s * 8] = bv;
            }
            __syncthreads();
            bf16x8 af[4], bfr[4];
            #pragma unroll
            for (int mt = 0; mt < 4; ++mt) af[mt]  = *(bf16x8*)&Al[((mq * 4 + mt) * 64 + lane) * 8];
            #pragma unroll
            for (int nt = 0; nt < 4; ++nt) bfr[nt] = *(bf16x8*)&Bl[((nq * 4 + nt) * 64 + lane) * 8];
            #pragma unroll
            for (int mt = 0; mt < 4; ++mt)
                #pragma unroll
                for (int nt = 0; nt < 4; ++nt)
                    acc[mt][nt] = __builtin_amdgcn_mfma_f32_16x16x32_bf16(af[mt], bfr[nt], acc[mt][nt], 0, 0, 0);
        }
        const int l15 = lane & 15, quad = lane >> 4;
        #pragma unroll
        for (int nt = 0; nt < 4; ++nt) {
            int col = n0 + nq * 64 + nt * 16 + l15;
            float bv = bias[col];
            #pragma unroll
            for (int mt = 0; mt < 4; ++mt)
                #pragma unroll
                for (int r = 0; r < 4; ++r) {
                    int row = r0 - next_r_base + mq * 64 + mt * 16 + quad * 4 + r;
                    xp_wr[(size_t)row * G4 + col] = (bf16_t)(acc[mt][nt][r] + bv);
                }
        }
        return;
    }

    // ---------------- step path ----------------
    const int w    = tid >> 6;                    // K-quarter index
    const int lane = tid & 63;
    const int bid  = blockIdx.x;
    const int q    = bid & 127;                   // packed col-block (32 cols)
    const int bh   = bid >> 7;                    // batch half

    const int col  = lane & 31;
    const int ksel = lane >> 5;
    const int gt   = (lane >> 3) & 3;  // 0:i 1:f 2:g 3:o
    const int jj   = lane & 7;

    int rrow[4];
    #pragma unroll
    for (int e = 0; e < 4; ++e) rrow[e] = e + 8 * w + 4 * ksel;

    // Loop-invariant B fragments: loaded once, live in VGPRs all chunk.
    const bf16_t* bb = whtf + ((size_t)q << 15) + (w << 13) + (lane << 3);
    bf16x8 bfr[16];
    #pragma unroll
    for (int i = 0; i < 16; ++i) bfr[i] = *(const bf16x8*)(bb + i * 512);

    // c-state in registers for the whole chunk (i-gate lanes only).
    float cst[4] = {0.f, 0.f, 0.f, 0.f};
    if (gt == 0) {
        #pragma unroll
        for (int e = 0; e < 4; ++e)
            cst[e] = cstbuf[(bh * 32 + rrow[e]) * H_DIM + q * 8 + jj];
    }

    const int abase = (bh << 15) + (w << 13) + (lane << 3);  // h A-frag base (bf16 elements)

    for (int tl = 0; tl < CHUNK; ++tl) {
        const int gstep = t_base + tl;

        // xp loads first: dispatch-constant data, overlaps the flag poll.
        const bf16_t* xp_t = xp_rd + (size_t)(tl * 64) * G4;
        bf16_t xpr[4];
        #pragma unroll
        for (int e = 0; e < 4; ++e)
            xpr[e] = xp_t[(size_t)(bh * 32 + rrow[e]) * G4 + q * 32 + col];

        // Wait until every producer of this batch-half has published h_{gstep}.
        // Wave 0 only, tight loop, 2 flags/lane, no block sync inside.
        if (w == 0) {
            const uint32_t target = (uint32_t)gstep;
            const uint32_t* fb = flags + (bh << 7);
            for (;;) {
                uint32_t f0 = __hip_atomic_load(fb + lane,      __ATOMIC_RELAXED, __HIP_MEMORY_SCOPE_AGENT);
                uint32_t f1 = __hip_atomic_load(fb + 64 + lane, __ATOMIC_RELAXED, __HIP_MEMORY_SCOPE_AGENT);
                if (__all((int)(f0 >= target) & (int)(f1 >= target))) break;
            }
        }
        __syncthreads();
        asm volatile("" ::: "memory");   // no hoisting of h loads above the poll

        // h loads: 32 relaxed agent u64 (L2-bypassing, coherent at L3).
        const uint64_t* hsrc = (const uint64_t*)(hbuf + ((gstep & 1) << 16) + abase);
        uint64_t hl0[16], hl1[16];
        #pragma unroll
        for (int i = 0; i < 16; ++i) {
            hl0[i] = __hip_atomic_load(hsrc + i * 128,     __ATOMIC_RELAXED, __HIP_MEMORY_SCOPE_AGENT);
            hl1[i] = __hip_atomic_load(hsrc + i * 128 + 1, __ATOMIC_RELAXED, __HIP_MEMORY_SCOPE_AGENT);
        }

        struct U2 { uint64_t a, b; };
        f32x16 acc0 = {}, acc1 = {}, acc2 = {}, acc3 = {};
        #pragma unroll
        for (int i = 0; i < 16; i += 4) {
            U2 t0{hl0[i + 0], hl1[i + 0]};
            U2 t1{hl0[i + 1], hl1[i + 1]};
            U2 t2{hl0[i + 2], hl1[i + 2]};
            U2 t3{hl0[i + 3], hl1[i + 3]};
            acc0 = __builtin_amdgcn_mfma_f32_32x32x16_bf16(__builtin_bit_cast(bf16x8, t0), bfr[i + 0], acc0, 0, 0, 0);
            acc1 = __builtin_amdgcn_mfma_f32_32x32x16_bf16(__builtin_bit_cast(bf16x8, t1), bfr[i + 1], acc1, 0, 0, 0);
            acc2 = __builtin_amdgcn_mfma_f32_32x32x16_bf16(__builtin_bit_cast(bf16x8, t2), bfr[i + 2], acc2, 0, 0, 0);
            acc3 = __builtin_amdgcn_mfma_f32_32x32x16_bf16(__builtin_bit_cast(bf16x8, t3), bfr[i + 3], acc3, 0, 0, 0);
        }
        f32x16 accs = acc0 + acc1 + acc2 + acc3;

        #pragma unroll
        for (int e = 0; e < 16; ++e) Pl[w][e][lane] = accs[e];
        __syncthreads();

        #pragma unroll
        for (int e = 0; e < 4; ++e) {
            int eg = w * 4 + e;
            float pre = Pl[0][eg][lane] + Pl[1][eg][lane] + Pl[2][eg][lane] + Pl[3][eg][lane];
            pre += (float)xpr[e];
            float a = (gt == 2) ? tanh_fast(pre) : sigm(pre);

            float fv = __shfl_xor(a, 8, 64);
            float gv = __shfl_xor(a, 16, 64);
            float ov = __shfl_xor(a, 24, 64);
            if (gt == 0) {
                float cn = fv * cst[e] + a * gv;
                float hv = ov * tanh_fast(cn);
                cst[e] = cn;
                Hlds[rrow[e] * 8 + jj] = (bf16_t)hv;
                if (write_out_last && tl == CHUNK - 1) {
                    int rowg = bh * 32 + rrow[e];
                    int j = q * 8 + jj;
                    out[rowg * H_DIM + j] = hv;            // h_T
                    out[65536 + rowg * H_DIM + j] = cn;    // c_T
                }
            }
        }
        __syncthreads();   // Hlds complete; also fences Pl reuse next step

        // Publish this WG's h slice, then its flag (after vmcnt(0) drain).
        if (w == 0) {
            uint64_t v = *(const uint64_t*)&Hlds[lane * 4];
            uint64_t* hdst = (uint64_t*)hbuf + (((gstep + 1) & 1) << 14)
                           + (bh << 13) + (q << 6) + lane;
            __hip_atomic_store(hdst, v, __ATOMIC_RELAXED, __HIP_MEMORY_SCOPE_AGENT);
            asm volatile("s_waitcnt vmcnt(0)" ::: "memory");
            if (lane == 0)
                __hip_atomic_store(&flags[(bh << 7) + q], (uint32_t)(gstep + 1),
                                   __ATOMIC_RELAXED, __HIP_MEMORY_SCOPE_AGENT);
        }
    }

    // c-state writeback for the next chunk (normal stores; dispatch-end release)
    if (gt == 0) {
        #pragma unroll
        for (int e = 0; e < 4; ++e)
            cstbuf[(bh * 32 + rrow[e]) * H_DIM + q * 8 + jj] = cst[e];
    }
}

extern "C" void kernel_launch(void* const* d_in, const int* in_sizes, int n_in,
                              void* d_out, int out_size, void* d_ws, size_t ws_size,
                              hipStream_t stream) {
    const float* x   = (const float*)d_in[0];
    const float* wii = (const float*)d_in[1];
    const float* bii = (const float*)d_in[2];
    const float* whi = (const float*)d_in[3];
    const float* bhi = (const float*)d_in[4];
    const float* wif = (const float*)d_in[5];
    const float* bif = (const float*)d_in[6];
    const float* whf = (const float*)d_in[7];
    const float* bhf = (const float*)d_in[8];
    const float* wig = (const float*)d_in[9];
    const float* big = (const float*)d_in[10];
    const float* whg = (const float*)d_in[11];
    const float* bhg = (const float*)d_in[12];
    const float* wio = (const float*)d_in[13];
    const float* bio = (const float*)d_in[14];
    const float* who = (const float*)d_in[15];
    const float* bho = (const float*)d_in[16];

    char* ws = (char*)d_ws;
    bf16_t*   wxt  = (bf16_t*)(ws + O_WXT);
    bf16_t*   whtf = (bf16_t*)(ws + O_WHTF);
    float*    bias = (float*)(ws + O_BIAS);
    float*    cstb = (float*)(ws + O_CST);
    bf16_t*   hbuf = (bf16_t*)(ws + O_HBUF);
    uint32_t* flg  = (uint32_t*)(ws + O_FLG);
    bf16_t*   xp   = (bf16_t*)(ws + O_XP);

    hipMemsetAsync(hbuf, 0, 256 * 1024, stream);   // both h slots = 0
    hipMemsetAsync(cstb, 0, 256 * 1024, stream);   // c0 = 0
    hipMemsetAsync(flg,  0, 4096, stream);         // flags = 0 (reset each replay)

    k_pack_wx<<<8192, 256, 0, stream>>>(wii, wif, wig, wio, wxt);
    k_pack_whf<<<16384, 256, 0, stream>>>(whi, whf, whg, who, whtf);
    k_pack_bias<<<16, 256, 0, stream>>>(bii, bhi, bif, bhf, big, bhg, bio, bho, bias);

    float* out = (float*)d_out;
    // chunk 0's xproj standalone
    k_xproj<<<dim3(32, CHUNK * 64 / 128), 256, 0, stream>>>(x, wxt, bias, xp, 0);

    for (int c = 0; c < NCHUNK; ++c) {
        int t_base      = c * CHUNK;
        int wol         = (c == NCHUNK - 1) ? 1 : 0;
        int has_next    = (c < NCHUNK - 1) ? 1 : 0;
        int next_r_base = (c + 1) * CHUNK * 64;
        bf16_t* xp_rd = xp + (size_t)(c & 1) * XPSLOT_ELEMS;
        bf16_t* xp_wr = xp + (size_t)((c + 1) & 1) * XPSLOT_ELEMS;
        void* args[] = { (void*)&x, (void*)&wxt, (void*)&bias, (void*)&whtf,
                         (void*)&xp_rd, (void*)&xp_wr, (void*)&hbuf, (void*)&cstb,
                         (void*)&out, (void*)&flg, (void*)&t_base, (void*)&wol,
                         (void*)&next_r_base, (void*)&has_next };
        hipError_t err = hipLaunchCooperativeKernel((const void*)k_fused, dim3(512), dim3(256),
                                                    args, 0, stream);
        if (err != hipSuccess) {
            k_fused<<<512, 256, 0, stream>>>(x, wxt, bias, whtf, xp_rd, xp_wr,
                                             hbuf, cstb, out, flg, t_base, wol,
                                             next_r_base, has_next);
        }
    }
}

// Round 6
// 3594.513 us; speedup vs baseline: 1.3324x; 1.2703x over previous
//
#include <hip/hip_runtime.h>
#include <hip/hip_bf16.h>
#include <stdint.h>

typedef __bf16 bf16_t;
typedef bf16_t bf16x8 __attribute__((ext_vector_type(8)));
typedef float  f32x4  __attribute__((ext_vector_type(4)));
typedef float  f32x16 __attribute__((ext_vector_type(16)));

#define I_DIM 512
#define H_DIM 1024
#define B_DIM 64
#define S_DIM 512
#define G4    4096   // 4*H
#define CHUNK 16     // steps per fused dispatch
#define NCHUNK (S_DIM / CHUNK)
#define XPSLOT_ELEMS ((size_t)CHUNK * 64 * G4)   // 1024*4096 bf16 = 8 MB

// ---------------- workspace layout (bytes) — total ~34 MB ----------------
#define O_WXT   0x0000000ULL  // [4096][512]  bf16 = 4 MB   (packed WxT, row-major)
#define O_WHTF  0x0400000ULL  // [128][64][64][8] bf16 = 8 MB (Wh in MFMA B-frag order)
#define O_BIAS  0x0C00000ULL  // [4096] f32 = 16 KB
#define O_CST   0x0C10000ULL  // [64][1024] f32 = 256 KB (c-state, chunk-boundary only)
#define O_HBUF  0x0D00000ULL  // 2 slots * 128 KB (h in A-frag order) = 256 KB
#define O_BAR   0x0D40000ULL  // 8 KB: two per-half barrier trees (monotonic counters)
#define O_XP    0x1200000ULL  // 2 slots * [1024][4096] bf16 = 16 MB

__device__ __forceinline__ float sigm(float x)      { return 1.f / (1.f + __expf(-x)); }
__device__ __forceinline__ float tanh_fast(float x) { return 1.f - 2.f / (__expf(2.f * x) + 1.f); }

// Packed gate-column permutation: packed col p = q*32 + g*8 + jj  <->  hidden j = q*8+jj, gate g (0:i 1:f 2:g 3:o)

__global__ void k_pack_wx(const float* __restrict__ w0, const float* __restrict__ w1,
                          const float* __restrict__ w2, const float* __restrict__ w3,
                          bf16_t* __restrict__ wxt) {
    int tid = blockIdx.x * 256 + threadIdx.x;
    int k = tid >> 12;
    int p = tid & 4095;
    int q = p >> 5, g = (p >> 3) & 3, jj = p & 7;
    int j = q * 8 + jj;
    const float* src = (g == 0) ? w0 : (g == 1) ? w1 : (g == 2) ? w2 : w3;
    wxt[(size_t)p * I_DIM + k] = (bf16_t)src[k * H_DIM + j];
}

// Wh -> global MFMA B-fragment order: whtf[q][ks][lane][8]
//   element = WhT[p = q*32 + (lane&31)][k = ks*16 + (lane>>5)*8 + e]
__global__ void k_pack_whf(const float* __restrict__ w0, const float* __restrict__ w1,
                           const float* __restrict__ w2, const float* __restrict__ w3,
                           bf16_t* __restrict__ whtf) {
    int idx = blockIdx.x * 256 + threadIdx.x;     // 0..4194303
    int e    = idx & 7;
    int lane = (idx >> 3) & 63;
    int ks   = (idx >> 9) & 63;
    int q    = idx >> 15;                          // 0..127
    int k = ks * 16 + (lane >> 5) * 8 + e;
    int c = lane & 31;
    int g = c >> 3, jj = c & 7;
    int j = q * 8 + jj;
    const float* src = (g == 0) ? w0 : (g == 1) ? w1 : (g == 2) ? w2 : w3;
    whtf[idx] = (bf16_t)src[k * H_DIM + j];
}

__global__ void k_pack_bias(const float* bi0, const float* bh0, const float* bi1, const float* bh1,
                            const float* bi2, const float* bh2, const float* bi3, const float* bh3,
                            float* __restrict__ bias) {
    int p = blockIdx.x * 256 + threadIdx.x;
    int q = p >> 5, g = (p >> 3) & 3, jj = p & 7;
    int j = q * 8 + jj;
    const float* a = (g == 0) ? bi0 : (g == 1) ? bi1 : (g == 2) ? bi2 : bi3;
    const float* b = (g == 0) ? bh0 : (g == 1) ? bh1 : (g == 2) ? bh2 : bh3;
    bias[p] = a[j] + b[j];
}

// ---------------- standalone x_proj GEMM (chunk 0 only) ----------------
__global__ __launch_bounds__(256, 2) void k_xproj(
    const float* __restrict__ x, const bf16_t* __restrict__ wxt,
    const float* __restrict__ bias, bf16_t* __restrict__ xp, int r_base)
{
    __shared__ __align__(16) bf16_t Al[8 * 64 * 8];
    __shared__ __align__(16) bf16_t Bl[8 * 64 * 8];
    const int tid = threadIdx.x;
    const int n0 = blockIdx.x * 128;
    const int r0 = r_base + blockIdx.y * 128;
    const int wv = tid >> 6;
    const int lane = tid & 63;
    const int mq = wv >> 1, nq = wv & 1;
    f32x4 acc[4][4] = {};

    for (int kk = 0; kk < I_DIM; kk += 32) {
        __syncthreads();
        #pragma unroll
        for (int sidx = 0; sidx < 2; ++sidx) {
            int s = tid + sidx * 256;
            int mt = s >> 6, l = s & 63;
            int m = l & 15, kb = (l >> 4) * 8;
            int r = r0 + mt * 16 + m;
            int b = r & 63, si = r >> 6;
            const float* gp = x + ((size_t)(b * S_DIM + si)) * I_DIM + kk + kb;
            float4 v0 = *(const float4*)gp;
            float4 v1 = *(const float4*)(gp + 4);
            bf16x8 a;
            a[0] = (bf16_t)v0.x; a[1] = (bf16_t)v0.y; a[2] = (bf16_t)v0.z; a[3] = (bf16_t)v0.w;
            a[4] = (bf16_t)v1.x; a[5] = (bf16_t)v1.y; a[6] = (bf16_t)v1.z; a[7] = (bf16_t)v1.w;
            *(bf16x8*)&Al[s * 8] = a;
            bf16x8 bv = *(const bf16x8*)(wxt + (size_t)(n0 + mt * 16 + m) * I_DIM + kk + kb);
            *(bf16x8*)&Bl[s * 8] = bv;
        }
        __syncthreads();
        bf16x8 af[4], bfr[4];
        #pragma unroll
        for (int mt = 0; mt < 4; ++mt) af[mt]  = *(bf16x8*)&Al[((mq * 4 + mt) * 64 + lane) * 8];
        #pragma unroll
        for (int nt = 0; nt < 4; ++nt) bfr[nt] = *(bf16x8*)&Bl[((nq * 4 + nt) * 64 + lane) * 8];
        #pragma unroll
        for (int mt = 0; mt < 4; ++mt)
            #pragma unroll
            for (int nt = 0; nt < 4; ++nt)
                acc[mt][nt] = __builtin_amdgcn_mfma_f32_16x16x32_bf16(af[mt], bfr[nt], acc[mt][nt], 0, 0, 0);
    }
    const int l15 = lane & 15, quad = lane >> 4;
    #pragma unroll
    for (int nt = 0; nt < 4; ++nt) {
        int col = n0 + nq * 64 + nt * 16 + l15;
        float bv = bias[col];
        #pragma unroll
        for (int mt = 0; mt < 4; ++mt)
            #pragma unroll
            for (int r = 0; r < 4; ++r) {
                int row = r0 - r_base + mq * 64 + mt * 16 + quad * 4 + r;
                xp[(size_t)row * G4 + col] = (bf16_t)(acc[mt][nt][r] + bv);
            }
    }
}

// ---------------- fused dispatch: 16 steps + next chunk's xproj ----------------
// R12: consolidation. Sync = R8's tree barrier (measured 4.93 us/step, the
// best of three mechanisms; flag-vector dataflow measured 8.3-8.6 across two
// poll styles — last-of-128-flags detection amplifies producer skew).
// Refinements vs R8: (a) separate barrier tree per batch-half (the two
// recurrences are independent; 16-arrival groups halve RMW serialization and
// decouple skew); (b) wave-0 vmcnt(0) drain replaces one block-wide
// __syncthreads before arrival. xproj fusion kept from R11 (proven): blocks
// 256..511 compute chunk c+1's xp into the other slot; dispatch boundary
// makes it visible. h loads issued UNCONDITIONALLY at loop top — previous
// episode's barrier (or dispatch boundary) already guarantees h_t published.
__global__ __launch_bounds__(256, 2) void k_fused(
    const float* __restrict__ x, const bf16_t* __restrict__ wxt,
    const float* __restrict__ bias, const bf16_t* __restrict__ whtf,
    const bf16_t* __restrict__ xp_rd, bf16_t* __restrict__ xp_wr,
    bf16_t* __restrict__ hbuf, float* __restrict__ cstbuf,
    float* __restrict__ out, uint32_t* __restrict__ bar,
    int t_base, int ep_base, int write_out_last, int next_r_base, int has_next)
{
    __shared__ float Pl[4][16][64];               // step: partials, 16 KB
    __shared__ __align__(16) bf16_t Hlds[256];    // step: h staging
    __shared__ __align__(16) bf16_t Al[8 * 64 * 8];  // xproj: A tile, 4 KB
    __shared__ __align__(16) bf16_t Bl[8 * 64 * 8];  // xproj: B tile, 4 KB
    const int tid  = threadIdx.x;

    if (blockIdx.x >= 256) {
        // ---------------- xproj path (next chunk) ----------------
        if (!has_next) return;
        const int xbid = blockIdx.x - 256;
        const int n0 = (xbid & 31) * 128;
        const int r0 = next_r_base + (xbid >> 5) * 128;
        const int wv = tid >> 6;
        const int lane = tid & 63;
        const int mq = wv >> 1, nq = wv & 1;
        f32x4 acc[4][4] = {};

        for (int kk = 0; kk < I_DIM; kk += 32) {
            __syncthreads();
            #pragma unroll
            for (int sidx = 0; sidx < 2; ++sidx) {
                int s = tid + sidx * 256;
                int mt = s >> 6, l = s & 63;
                int m = l & 15, kb = (l >> 4) * 8;
                int r = r0 + mt * 16 + m;
                int b = r & 63, si = r >> 6;
                const float* gp = x + ((size_t)(b * S_DIM + si)) * I_DIM + kk + kb;
                float4 v0 = *(const float4*)gp;
                float4 v1 = *(const float4*)(gp + 4);
                bf16x8 a;
                a[0] = (bf16_t)v0.x; a[1] = (bf16_t)v0.y; a[2] = (bf16_t)v0.z; a[3] = (bf16_t)v0.w;
                a[4] = (bf16_t)v1.x; a[5] = (bf16_t)v1.y; a[6] = (bf16_t)v1.z; a[7] = (bf16_t)v1.w;
                *(bf16x8*)&Al[s * 8] = a;
                bf16x8 bv = *(const bf16x8*)(wxt + (size_t)(n0 + mt * 16 + m) * I_DIM + kk + kb);
                *(bf16x8*)&Bl[s * 8] = bv;
            }
            __syncthreads();
            bf16x8 af[4], bfr[4];
            #pragma unroll
            for (int mt = 0; mt < 4; ++mt) af[mt]  = *(bf16x8*)&Al[((mq * 4 + mt) * 64 + lane) * 8];
            #pragma unroll
            for (int nt = 0; nt < 4; ++nt) bfr[nt] = *(bf16x8*)&Bl[((nq * 4 + nt) * 64 + lane) * 8];
            #pragma unroll
            for (int mt = 0; mt < 4; ++mt)
                #pragma unroll
                for (int nt = 0; nt < 4; ++nt)
                    acc[mt][nt] = __builtin_amdgcn_mfma_f32_16x16x32_bf16(af[mt], bfr[nt], acc[mt][nt], 0, 0, 0);
        }
        const int l15 = lane & 15, quad = lane >> 4;
        #pragma unroll
        for (int nt = 0; nt < 4; ++nt) {
            int col = n0 + nq * 64 + nt * 16 + l15;
            float bv = bias[col];
            #pragma unroll
            for (int mt = 0; mt < 4; ++mt)
                #pragma unroll
                for (int r = 0; r < 4; ++r) {
                    int row = r0 - next_r_base + mq * 64 + mt * 16 + quad * 4 + r;
                    xp_wr[(size_t)row * G4 + col] = (bf16_t)(acc[mt][nt][r] + bv);
                }
        }
        return;
    }

    // ---------------- step path ----------------
    const int w    = tid >> 6;                    // K-quarter index
    const int lane = tid & 63;
    const int bid  = blockIdx.x;
    const int q    = bid & 127;                   // packed col-block (32 cols)
    const int bh   = bid >> 7;                    // batch half

    const int col  = lane & 31;
    const int ksel = lane >> 5;
    const int gt   = (lane >> 3) & 3;  // 0:i 1:f 2:g 3:o
    const int jj   = lane & 7;

    // Per-half barrier tree counters (all monotonic, u32, 64-u32 spaced):
    //   group[bh][g]: bar[(bh*8+g)*64], g = q&7, 16 arrivals/episode
    //   root[bh]:     bar[1024 + bh*64], 8 leader increments/episode
    //   epoch[bh]:    bar[1152 + bh*64], +1/episode
    uint32_t* grp   = bar + ((bh * 8 + (q & 7)) << 6);
    uint32_t* root  = bar + 1024 + (bh << 6);
    uint32_t* epoch = bar + 1152 + (bh << 6);

    int rrow[4];
    #pragma unroll
    for (int e = 0; e < 4; ++e) rrow[e] = e + 8 * w + 4 * ksel;

    // Loop-invariant B fragments: loaded once, live in VGPRs all chunk.
    const bf16_t* bb = whtf + ((size_t)q << 15) + (w << 13) + (lane << 3);
    bf16x8 bfr[16];
    #pragma unroll
    for (int i = 0; i < 16; ++i) bfr[i] = *(const bf16x8*)(bb + i * 512);

    // c-state in registers for the whole chunk (i-gate lanes only).
    float cst[4] = {0.f, 0.f, 0.f, 0.f};
    if (gt == 0) {
        #pragma unroll
        for (int e = 0; e < 4; ++e)
            cst[e] = cstbuf[(bh * 32 + rrow[e]) * H_DIM + q * 8 + jj];
    }

    const int abase = (bh << 15) + (w << 13) + (lane << 3);  // h A-frag base (bf16 elements)

    for (int tl = 0; tl < CHUNK; ++tl) {
        const int gstep = t_base + tl;

        // h loads upfront — availability guaranteed by previous episode's
        // barrier (or the dispatch boundary for tl==0). No poll in series.
        const uint64_t* hsrc = (const uint64_t*)(hbuf + ((gstep & 1) << 16) + abase);
        uint64_t hl0[16], hl1[16];
        #pragma unroll
        for (int i = 0; i < 16; ++i) {
            hl0[i] = __hip_atomic_load(hsrc + i * 128,     __ATOMIC_RELAXED, __HIP_MEMORY_SCOPE_AGENT);
            hl1[i] = __hip_atomic_load(hsrc + i * 128 + 1, __ATOMIC_RELAXED, __HIP_MEMORY_SCOPE_AGENT);
        }

        const bf16_t* xp_t = xp_rd + (size_t)(tl * 64) * G4;
        bf16_t xpr[4];
        #pragma unroll
        for (int e = 0; e < 4; ++e)
            xpr[e] = xp_t[(size_t)(bh * 32 + rrow[e]) * G4 + q * 32 + col];

        struct U2 { uint64_t a, b; };
        f32x16 acc0 = {}, acc1 = {}, acc2 = {}, acc3 = {};
        #pragma unroll
        for (int i = 0; i < 16; i += 4) {
            U2 t0{hl0[i + 0], hl1[i + 0]};
            U2 t1{hl0[i + 1], hl1[i + 1]};
            U2 t2{hl0[i + 2], hl1[i + 2]};
            U2 t3{hl0[i + 3], hl1[i + 3]};
            acc0 = __builtin_amdgcn_mfma_f32_32x32x16_bf16(__builtin_bit_cast(bf16x8, t0), bfr[i + 0], acc0, 0, 0, 0);
            acc1 = __builtin_amdgcn_mfma_f32_32x32x16_bf16(__builtin_bit_cast(bf16x8, t1), bfr[i + 1], acc1, 0, 0, 0);
            acc2 = __builtin_amdgcn_mfma_f32_32x32x16_bf16(__builtin_bit_cast(bf16x8, t2), bfr[i + 2], acc2, 0, 0, 0);
            acc3 = __builtin_amdgcn_mfma_f32_32x32x16_bf16(__builtin_bit_cast(bf16x8, t3), bfr[i + 3], acc3, 0, 0, 0);
        }
        f32x16 accs = acc0 + acc1 + acc2 + acc3;

        #pragma unroll
        for (int e = 0; e < 16; ++e) Pl[w][e][lane] = accs[e];
        __syncthreads();

        #pragma unroll
        for (int e = 0; e < 4; ++e) {
            int eg = w * 4 + e;
            float pre = Pl[0][eg][lane] + Pl[1][eg][lane] + Pl[2][eg][lane] + Pl[3][eg][lane];
            pre += (float)xpr[e];
            float a = (gt == 2) ? tanh_fast(pre) : sigm(pre);

            float fv = __shfl_xor(a, 8, 64);
            float gv = __shfl_xor(a, 16, 64);
            float ov = __shfl_xor(a, 24, 64);
            if (gt == 0) {
                float cn = fv * cst[e] + a * gv;
                float hv = ov * tanh_fast(cn);
                cst[e] = cn;
                Hlds[rrow[e] * 8 + jj] = (bf16_t)hv;
                if (write_out_last && tl == CHUNK - 1) {
                    int rowg = bh * 32 + rrow[e];
                    int j = q * 8 + jj;
                    out[rowg * H_DIM + j] = hv;            // h_T
                    out[65536 + rowg * H_DIM + j] = cn;    // c_T
                }
            }
        }
        __syncthreads();   // Hlds complete; also fences Pl reuse next step

        // Publish h slice (wave 0), drain in-wave, arrive + poll (tid 0).
        if (w == 0) {
            uint64_t v = *(const uint64_t*)&Hlds[lane * 4];
            uint64_t* hdst = (uint64_t*)hbuf + (((gstep + 1) & 1) << 14)
                           + (bh << 13) + (q << 6) + lane;
            __hip_atomic_store(hdst, v, __ATOMIC_RELAXED, __HIP_MEMORY_SCOPE_AGENT);
            if (tl < CHUNK - 1) {
                asm volatile("s_waitcnt vmcnt(0)" ::: "memory");  // h store at L3
                if (lane == 0) {
                    uint32_t old = __hip_atomic_fetch_add(grp, 1u,
                                                          __ATOMIC_RELAXED, __HIP_MEMORY_SCOPE_AGENT);
                    if ((old & 15u) == 15u) {                    // 16 arrivals -> leader
                        uint32_t old2 = __hip_atomic_fetch_add(root, 1u,
                                                               __ATOMIC_RELAXED, __HIP_MEMORY_SCOPE_AGENT);
                        if ((old2 & 7u) == 7u)                   // last of 8 groups
                            __hip_atomic_fetch_add(epoch, 1u,
                                                   __ATOMIC_RELAXED, __HIP_MEMORY_SCOPE_AGENT);
                    }
                    uint32_t target = (uint32_t)(ep_base + tl + 1);
                    while (__hip_atomic_load(epoch, __ATOMIC_RELAXED,
                                             __HIP_MEMORY_SCOPE_AGENT) < target) {}
                }
            }
        }
        if (tl < CHUNK - 1) __syncthreads();   // release all waves
    }

    // c-state writeback for the next chunk (normal stores; dispatch-end release)
    if (gt == 0) {
        #pragma unroll
        for (int e = 0; e < 4; ++e)
            cstbuf[(bh * 32 + rrow[e]) * H_DIM + q * 8 + jj] = cst[e];
    }
}

extern "C" void kernel_launch(void* const* d_in, const int* in_sizes, int n_in,
                              void* d_out, int out_size, void* d_ws, size_t ws_size,
                              hipStream_t stream) {
    const float* x   = (const float*)d_in[0];
    const float* wii = (const float*)d_in[1];
    const float* bii = (const float*)d_in[2];
    const float* whi = (const float*)d_in[3];
    const float* bhi = (const float*)d_in[4];
    const float* wif = (const float*)d_in[5];
    const float* bif = (const float*)d_in[6];
    const float* whf = (const float*)d_in[7];
    const float* bhf = (const float*)d_in[8];
    const float* wig = (const float*)d_in[9];
    const float* big = (const float*)d_in[10];
    const float* whg = (const float*)d_in[11];
    const float* bhg = (const float*)d_in[12];
    const float* wio = (const float*)d_in[13];
    const float* bio = (const float*)d_in[14];
    const float* who = (const float*)d_in[15];
    const float* bho = (const float*)d_in[16];

    char* ws = (char*)d_ws;
    bf16_t*   wxt  = (bf16_t*)(ws + O_WXT);
    bf16_t*   whtf = (bf16_t*)(ws + O_WHTF);
    float*    bias = (float*)(ws + O_BIAS);
    float*    cstb = (float*)(ws + O_CST);
    bf16_t*   hbuf = (bf16_t*)(ws + O_HBUF);
    uint32_t* bar  = (uint32_t*)(ws + O_BAR);
    bf16_t*   xp   = (bf16_t*)(ws + O_XP);

    hipMemsetAsync(hbuf, 0, 256 * 1024, stream);   // both h slots = 0
    hipMemsetAsync(cstb, 0, 256 * 1024, stream);   // c0 = 0
    hipMemsetAsync(bar,  0, 8192, stream);         // barrier counters (reset each replay)

    k_pack_wx<<<8192, 256, 0, stream>>>(wii, wif, wig, wio, wxt);
    k_pack_whf<<<16384, 256, 0, stream>>>(whi, whf, whg, who, whtf);
    k_pack_bias<<<16, 256, 0, stream>>>(bii, bhi, bif, bhf, big, bhg, bio, bho, bias);

    float* out = (float*)d_out;
    // chunk 0's xproj standalone
    k_xproj<<<dim3(32, CHUNK * 64 / 128), 256, 0, stream>>>(x, wxt, bias, xp, 0);

    for (int c = 0; c < NCHUNK; ++c) {
        int t_base      = c * CHUNK;
        int ep_base     = c * (CHUNK - 1);
        int wol         = (c == NCHUNK - 1) ? 1 : 0;
        int has_next    = (c < NCHUNK - 1) ? 1 : 0;
        int next_r_base = (c + 1) * CHUNK * 64;
        bf16_t* xp_rd = xp + (size_t)(c & 1) * XPSLOT_ELEMS;
        bf16_t* xp_wr = xp + (size_t)((c + 1) & 1) * XPSLOT_ELEMS;
        void* args[] = { (void*)&x, (void*)&wxt, (void*)&bias, (void*)&whtf,
                         (void*)&xp_rd, (void*)&xp_wr, (void*)&hbuf, (void*)&cstb,
                         (void*)&out, (void*)&bar, (void*)&t_base, (void*)&ep_base,
                         (void*)&wol, (void*)&next_r_base, (void*)&has_next };
        hipError_t err = hipLaunchCooperativeKernel((const void*)k_fused, dim3(512), dim3(256),
                                                    args, 0, stream);
        if (err != hipSuccess) {
            k_fused<<<512, 256, 0, stream>>>(x, wxt, bias, whtf, xp_rd, xp_wr,
                                             hbuf, cstb, out, bar, t_base, ep_base,
                                             wol, next_r_base, has_next);
        }
    }
}

// Round 7
// 3171.203 us; speedup vs baseline: 1.5103x; 1.1335x over previous
//
#include <hip/hip_runtime.h>
#include <hip/hip_bf16.h>
#include <stdint.h>

typedef __bf16 bf16_t;
typedef bf16_t bf16x8 __attribute__((ext_vector_type(8)));
typedef float  f32x4  __attribute__((ext_vector_type(4)));
typedef float  f32x16 __attribute__((ext_vector_type(16)));

#define I_DIM 512
#define H_DIM 1024
#define B_DIM 64
#define S_DIM 512
#define G4    4096   // 4*H
#define CHUNK 16     // steps per xp ring slot
#define NCHUNK (S_DIM / CHUNK)
#define XPSLOT_ELEMS ((size_t)CHUNK * 64 * G4)   // 1024*4096 bf16 = 8 MB

// ---------------- workspace layout (bytes) — total ~34 MB ----------------
#define O_WXT   0x0000000ULL  // [4096][512]  bf16 = 4 MB   (packed WxT, row-major)
#define O_WHTF  0x0400000ULL  // [128][64][64][8] bf16 = 8 MB (Wh in MFMA B-frag order)
#define O_BIAS  0x0C00000ULL  // [4096] f32 = 16 KB
#define O_HBUF  0x0D00000ULL  // 2 slots * 128 KB (h in A-frag order) = 256 KB
#define O_BAR   0x0D40000ULL  // 32 KB counters: tree barrier + xp_done[] + consumed[]
#define O_XP    0x1200000ULL  // 2 slots * [1024][4096] bf16 = 16 MB

// bar[] u32 indices (64-spaced to avoid false sharing)
#define XPD_IDX(c)  (2048 + (c) * 64)   // xp chunk c published (256 arrivals)
#define CONS_IDX(c) (4096 + (c) * 64)   // xp chunk c consumed  (256 arrivals)

__device__ __forceinline__ float sigm(float x)      { return 1.f / (1.f + __expf(-x)); }
__device__ __forceinline__ float tanh_fast(float x) { return 1.f - 2.f / (__expf(2.f * x) + 1.f); }

// Packed gate-column permutation: packed col p = q*32 + g*8 + jj  <->  hidden j = q*8+jj, gate g (0:i 1:f 2:g 3:o)

__global__ void k_pack_wx(const float* __restrict__ w0, const float* __restrict__ w1,
                          const float* __restrict__ w2, const float* __restrict__ w3,
                          bf16_t* __restrict__ wxt) {
    int tid = blockIdx.x * 256 + threadIdx.x;
    int k = tid >> 12;
    int p = tid & 4095;
    int q = p >> 5, g = (p >> 3) & 3, jj = p & 7;
    int j = q * 8 + jj;
    const float* src = (g == 0) ? w0 : (g == 1) ? w1 : (g == 2) ? w2 : w3;
    wxt[(size_t)p * I_DIM + k] = (bf16_t)src[k * H_DIM + j];
}

// Wh -> global MFMA B-fragment order: whtf[q][ks][lane][8]
//   element = WhT[p = q*32 + (lane&31)][k = ks*16 + (lane>>5)*8 + e]
__global__ void k_pack_whf(const float* __restrict__ w0, const float* __restrict__ w1,
                           const float* __restrict__ w2, const float* __restrict__ w3,
                           bf16_t* __restrict__ whtf) {
    int idx = blockIdx.x * 256 + threadIdx.x;     // 0..4194303
    int e    = idx & 7;
    int lane = (idx >> 3) & 63;
    int ks   = (idx >> 9) & 63;
    int q    = idx >> 15;                          // 0..127
    int k = ks * 16 + (lane >> 5) * 8 + e;
    int c = lane & 31;
    int g = c >> 3, jj = c & 7;
    int j = q * 8 + jj;
    const float* src = (g == 0) ? w0 : (g == 1) ? w1 : (g == 2) ? w2 : w3;
    whtf[idx] = (bf16_t)src[k * H_DIM + j];
}

__global__ void k_pack_bias(const float* bi0, const float* bh0, const float* bi1, const float* bh1,
                            const float* bi2, const float* bh2, const float* bi3, const float* bh3,
                            float* __restrict__ bias) {
    int p = blockIdx.x * 256 + threadIdx.x;
    int q = p >> 5, g = (p >> 3) & 3, jj = p & 7;
    int j = q * 8 + jj;
    const float* a = (g == 0) ? bi0 : (g == 1) ? bi1 : (g == 2) ? bi2 : bi3;
    const float* b = (g == 0) ? bh0 : (g == 1) ? bh1 : (g == 2) ? bh2 : bh3;
    bias[p] = a[j] + b[j];
}

// ---------------- the whole LSTM in ONE persistent dispatch ----------------
// R13: launch-tax elimination. R12 ledger: 32x89.8=2874 exec but 3594 total
// -> ~16us/dispatch overhead x36. One dispatch removes it. WGs 0..255: step
// path, 512 steps flat; B-frags loaded ONCE (512 steps), c-state in regs the
// whole sequence (cstbuf deleted). WGs 256..511: xproj producers, chunk sc
// into xp ring slot sc&1, paced by coarse counters (poll 1x per 16 steps):
//   producer: agent u16 atomic stores -> vmcnt(0) -> syncthreads ->
//             xp_done[sc] += 1 (256 arrivals). Waits consumed[sc-2]==256
//             before overwriting a slot.
//   consumer: poll xp_done[c]==256 at chunk entry; xpr reads via agent u16
//             atomic loads (L2-bypass; xp produced mid-dispatch on other
//             XCDs -> plain loads could see stale L2).
// Per-step h sync: R12 per-half tree barrier, held constant this round.
// Deadlock-safe even as plain launch: VGPR<=128, LDS 33KB -> 2 blocks/CU
// capacity = 512 = grid, all co-resident regardless of dispatch order.
__global__ __launch_bounds__(256, 2) void k_mega(
    const float* __restrict__ x, const bf16_t* __restrict__ wxt,
    const float* __restrict__ bias, const bf16_t* __restrict__ whtf,
    bf16_t* __restrict__ xp, bf16_t* __restrict__ hbuf,
    float* __restrict__ out, uint32_t* __restrict__ bar)
{
    __shared__ float Pl[4][16][64];               // step: partials, 16 KB
    __shared__ __align__(16) bf16_t Hlds[256];    // step: h staging
    __shared__ __align__(16) bf16_t Al[8 * 64 * 8];  // xproj: A tile, 8 KB
    __shared__ __align__(16) bf16_t Bl[8 * 64 * 8];  // xproj: B tile, 8 KB
    const int tid  = threadIdx.x;

    if (blockIdx.x >= 256) {
        // ---------------- xproj producer path ----------------
        const int xbid = blockIdx.x - 256;        // 0..255
        const int n0 = (xbid & 31) * 128;         // col tile
        const int rt = (xbid >> 5) * 128;         // row tile within chunk (0..896)
        const int wv = tid >> 6;
        const int lane = tid & 63;
        const int mq = wv >> 1, nq = wv & 1;
        const int l15 = lane & 15, quad = lane >> 4;

        for (int sc = 0; sc < NCHUNK; ++sc) {
            // Slot reuse gate: chunk sc writes slot sc&1, previously holding
            // chunk sc-2 — wait until all 256 step WGs consumed it.
            if (sc >= 2) {
                if (tid == 0) {
                    while (__hip_atomic_load(&bar[CONS_IDX(sc - 2)], __ATOMIC_RELAXED,
                                             __HIP_MEMORY_SCOPE_AGENT) < 256u)
                        __builtin_amdgcn_s_sleep(2);
                }
                __syncthreads();
            }
            bf16_t* xps = xp + (size_t)(sc & 1) * XPSLOT_ELEMS;
            const int r_base = sc * (CHUNK * 64);

            f32x4 acc[4][4] = {};
            for (int kk = 0; kk < I_DIM; kk += 32) {
                __syncthreads();
                #pragma unroll
                for (int sidx = 0; sidx < 2; ++sidx) {
                    int s = tid + sidx * 256;
                    int mt = s >> 6, l = s & 63;
                    int m = l & 15, kb = (l >> 4) * 8;
                    int r = r_base + rt + mt * 16 + m;
                    int b = r & 63, si = r >> 6;
                    const float* gp = x + ((size_t)(b * S_DIM + si)) * I_DIM + kk + kb;
                    float4 v0 = *(const float4*)gp;
                    float4 v1 = *(const float4*)(gp + 4);
                    bf16x8 a;
                    a[0] = (bf16_t)v0.x; a[1] = (bf16_t)v0.y; a[2] = (bf16_t)v0.z; a[3] = (bf16_t)v0.w;
                    a[4] = (bf16_t)v1.x; a[5] = (bf16_t)v1.y; a[6] = (bf16_t)v1.z; a[7] = (bf16_t)v1.w;
                    *(bf16x8*)&Al[s * 8] = a;
                    bf16x8 bv = *(const bf16x8*)(wxt + (size_t)(n0 + mt * 16 + m) * I_DIM + kk + kb);
                    *(bf16x8*)&Bl[s * 8] = bv;
                }
                __syncthreads();
                bf16x8 af[4], bfr[4];
                #pragma unroll
                for (int mt = 0; mt < 4; ++mt) af[mt]  = *(bf16x8*)&Al[((mq * 4 + mt) * 64 + lane) * 8];
                #pragma unroll
                for (int nt = 0; nt < 4; ++nt) bfr[nt] = *(bf16x8*)&Bl[((nq * 4 + nt) * 64 + lane) * 8];
                #pragma unroll
                for (int mt = 0; mt < 4; ++mt)
                    #pragma unroll
                    for (int nt = 0; nt < 4; ++nt)
                        acc[mt][nt] = __builtin_amdgcn_mfma_f32_16x16x32_bf16(af[mt], bfr[nt], acc[mt][nt], 0, 0, 0);
            }
            // Epilogue: agent-scope u16 stores (coherent for mid-dispatch read)
            #pragma unroll
            for (int nt = 0; nt < 4; ++nt) {
                int colg = n0 + nq * 64 + nt * 16 + l15;
                float bv = bias[colg];
                #pragma unroll
                for (int mt = 0; mt < 4; ++mt)
                    #pragma unroll
                    for (int r = 0; r < 4; ++r) {
                        int row = rt + mq * 64 + mt * 16 + quad * 4 + r;  // within chunk
                        bf16_t hb = (bf16_t)(acc[mt][nt][r] + bv);
                        __hip_atomic_store((uint16_t*)(xps + (size_t)row * G4 + colg),
                                           __builtin_bit_cast(unsigned short, hb),
                                           __ATOMIC_RELAXED, __HIP_MEMORY_SCOPE_AGENT);
                    }
            }
            asm volatile("s_waitcnt vmcnt(0)" ::: "memory");  // all lanes drained
            __syncthreads();                                   // all waves drained
            if (tid == 0)
                __hip_atomic_fetch_add(&bar[XPD_IDX(sc)], 1u,
                                       __ATOMIC_RELAXED, __HIP_MEMORY_SCOPE_AGENT);
        }
        return;
    }

    // ---------------- step path ----------------
    const int w    = tid >> 6;                    // K-quarter index
    const int lane = tid & 63;
    const int bid  = blockIdx.x;
    const int q    = bid & 127;                   // packed col-block (32 cols)
    const int bh   = bid >> 7;                    // batch half

    const int col  = lane & 31;
    const int ksel = lane >> 5;
    const int gt   = (lane >> 3) & 3;  // 0:i 1:f 2:g 3:o
    const int jj   = lane & 7;

    // Per-half barrier tree counters (monotonic u32, 64-spaced):
    uint32_t* grp   = bar + ((bh * 8 + (q & 7)) << 6);
    uint32_t* root  = bar + 1024 + (bh << 6);
    uint32_t* epoch = bar + 1152 + (bh << 6);

    int rrow[4];
    #pragma unroll
    for (int e = 0; e < 4; ++e) rrow[e] = e + 8 * w + 4 * ksel;

    // Loop-invariant B fragments: loaded ONCE for all 512 steps.
    const bf16_t* bb = whtf + ((size_t)q << 15) + (w << 13) + (lane << 3);
    bf16x8 bfr[16];
    #pragma unroll
    for (int i = 0; i < 16; ++i) bfr[i] = *(const bf16x8*)(bb + i * 512);

    // c-state in registers for the ENTIRE sequence (i-gate lanes only).
    float cst[4] = {0.f, 0.f, 0.f, 0.f};

    const int abase = (bh << 15) + (w << 13) + (lane << 3);  // h A-frag base (bf16 elements)

    for (int c = 0; c < NCHUNK; ++c) {
        // Wait for xp chunk c to be fully published (coarse, 1x per 16 steps).
        if (tid == 0) {
            while (__hip_atomic_load(&bar[XPD_IDX(c)], __ATOMIC_RELAXED,
                                     __HIP_MEMORY_SCOPE_AGENT) < 256u)
                __builtin_amdgcn_s_sleep(2);
        }
        __syncthreads();
        const uint16_t* xpc = (const uint16_t*)(xp + (size_t)(c & 1) * XPSLOT_ELEMS);

        for (int tl = 0; tl < CHUNK; ++tl) {
            const int t = c * CHUNK + tl;

            // h loads upfront — availability guaranteed by previous step's barrier.
            const uint64_t* hsrc = (const uint64_t*)(hbuf + ((t & 1) << 16) + abase);
            uint64_t hl0[16], hl1[16];
            #pragma unroll
            for (int i = 0; i < 16; ++i) {
                hl0[i] = __hip_atomic_load(hsrc + i * 128,     __ATOMIC_RELAXED, __HIP_MEMORY_SCOPE_AGENT);
                hl1[i] = __hip_atomic_load(hsrc + i * 128 + 1, __ATOMIC_RELAXED, __HIP_MEMORY_SCOPE_AGENT);
            }

            // xpr: agent u16 loads (xp produced mid-dispatch on other XCDs)
            bf16_t xpr[4];
            #pragma unroll
            for (int e = 0; e < 4; ++e) {
                unsigned short v = __hip_atomic_load(
                    &xpc[(size_t)(tl * 64 + bh * 32 + rrow[e]) * G4 + q * 32 + col],
                    __ATOMIC_RELAXED, __HIP_MEMORY_SCOPE_AGENT);
                xpr[e] = __builtin_bit_cast(bf16_t, v);
            }

            struct U2 { uint64_t a, b; };
            f32x16 acc0 = {}, acc1 = {}, acc2 = {}, acc3 = {};
            #pragma unroll
            for (int i = 0; i < 16; i += 4) {
                U2 t0{hl0[i + 0], hl1[i + 0]};
                U2 t1{hl0[i + 1], hl1[i + 1]};
                U2 t2{hl0[i + 2], hl1[i + 2]};
                U2 t3{hl0[i + 3], hl1[i + 3]};
                acc0 = __builtin_amdgcn_mfma_f32_32x32x16_bf16(__builtin_bit_cast(bf16x8, t0), bfr[i + 0], acc0, 0, 0, 0);
                acc1 = __builtin_amdgcn_mfma_f32_32x32x16_bf16(__builtin_bit_cast(bf16x8, t1), bfr[i + 1], acc1, 0, 0, 0);
                acc2 = __builtin_amdgcn_mfma_f32_32x32x16_bf16(__builtin_bit_cast(bf16x8, t2), bfr[i + 2], acc2, 0, 0, 0);
                acc3 = __builtin_amdgcn_mfma_f32_32x32x16_bf16(__builtin_bit_cast(bf16x8, t3), bfr[i + 3], acc3, 0, 0, 0);
            }
            f32x16 accs = acc0 + acc1 + acc2 + acc3;

            #pragma unroll
            for (int e = 0; e < 16; ++e) Pl[w][e][lane] = accs[e];
            __syncthreads();

            #pragma unroll
            for (int e = 0; e < 4; ++e) {
                int eg = w * 4 + e;
                float pre = Pl[0][eg][lane] + Pl[1][eg][lane] + Pl[2][eg][lane] + Pl[3][eg][lane];
                pre += (float)xpr[e];
                float a = (gt == 2) ? tanh_fast(pre) : sigm(pre);

                float fv = __shfl_xor(a, 8, 64);
                float gv = __shfl_xor(a, 16, 64);
                float ov = __shfl_xor(a, 24, 64);
                if (gt == 0) {
                    float cn = fv * cst[e] + a * gv;
                    float hv = ov * tanh_fast(cn);
                    cst[e] = cn;
                    Hlds[rrow[e] * 8 + jj] = (bf16_t)hv;
                    if (t == S_DIM - 1) {
                        int rowg = bh * 32 + rrow[e];
                        int j = q * 8 + jj;
                        out[rowg * H_DIM + j] = hv;            // h_T
                        out[65536 + rowg * H_DIM + j] = cn;    // c_T
                    }
                }
            }
            __syncthreads();   // Hlds complete; also fences Pl reuse next step

            // Publish h slice (wave 0), drain, tree arrive + poll (lane 0).
            if (w == 0) {
                uint64_t v = *(const uint64_t*)&Hlds[lane * 4];
                uint64_t* hdst = (uint64_t*)hbuf + (((t + 1) & 1) << 14)
                               + (bh << 13) + (q << 6) + lane;
                __hip_atomic_store(hdst, v, __ATOMIC_RELAXED, __HIP_MEMORY_SCOPE_AGENT);
                if (t < S_DIM - 1) {
                    asm volatile("s_waitcnt vmcnt(0)" ::: "memory");  // h store at L3
                    if (lane == 0) {
                        uint32_t old = __hip_atomic_fetch_add(grp, 1u,
                                                              __ATOMIC_RELAXED, __HIP_MEMORY_SCOPE_AGENT);
                        if ((old & 15u) == 15u) {                    // 16 arrivals -> leader
                            uint32_t old2 = __hip_atomic_fetch_add(root, 1u,
                                                                   __ATOMIC_RELAXED, __HIP_MEMORY_SCOPE_AGENT);
                            if ((old2 & 7u) == 7u)                   // last of 8 groups
                                __hip_atomic_fetch_add(epoch, 1u,
                                                       __ATOMIC_RELAXED, __HIP_MEMORY_SCOPE_AGENT);
                        }
                        uint32_t target = (uint32_t)(t + 1);
                        while (__hip_atomic_load(epoch, __ATOMIC_RELAXED,
                                                 __HIP_MEMORY_SCOPE_AGENT) < target) {}
                    }
                }
            }
            if (t < S_DIM - 1) __syncthreads();   // release all waves
        }

        // Chunk consumed: xproj may overwrite this xp slot (for chunk c+2).
        if (tid == 0)
            __hip_atomic_fetch_add(&bar[CONS_IDX(c)], 1u,
                                   __ATOMIC_RELAXED, __HIP_MEMORY_SCOPE_AGENT);
    }
}

extern "C" void kernel_launch(void* const* d_in, const int* in_sizes, int n_in,
                              void* d_out, int out_size, void* d_ws, size_t ws_size,
                              hipStream_t stream) {
    const float* x   = (const float*)d_in[0];
    const float* wii = (const float*)d_in[1];
    const float* bii = (const float*)d_in[2];
    const float* whi = (const float*)d_in[3];
    const float* bhi = (const float*)d_in[4];
    const float* wif = (const float*)d_in[5];
    const float* bif = (const float*)d_in[6];
    const float* whf = (const float*)d_in[7];
    const float* bhf = (const float*)d_in[8];
    const float* wig = (const float*)d_in[9];
    const float* big = (const float*)d_in[10];
    const float* whg = (const float*)d_in[11];
    const float* bhg = (const float*)d_in[12];
    const float* wio = (const float*)d_in[13];
    const float* bio = (const float*)d_in[14];
    const float* who = (const float*)d_in[15];
    const float* bho = (const float*)d_in[16];

    char* ws = (char*)d_ws;
    bf16_t*   wxt  = (bf16_t*)(ws + O_WXT);
    bf16_t*   whtf = (bf16_t*)(ws + O_WHTF);
    float*    bias = (float*)(ws + O_BIAS);
    bf16_t*   hbuf = (bf16_t*)(ws + O_HBUF);
    uint32_t* bar  = (uint32_t*)(ws + O_BAR);
    bf16_t*   xp   = (bf16_t*)(ws + O_XP);

    hipMemsetAsync(hbuf, 0, 256 * 1024, stream);   // both h slots = 0 (h0)
    hipMemsetAsync(bar,  0, 32 * 1024, stream);    // all counters (reset each replay)

    k_pack_wx<<<8192, 256, 0, stream>>>(wii, wif, wig, wio, wxt);
    k_pack_whf<<<16384, 256, 0, stream>>>(whi, whf, whg, who, whtf);
    k_pack_bias<<<16, 256, 0, stream>>>(bii, bhi, bif, bhf, big, bhg, bio, bho, bias);

    float* out = (float*)d_out;
    void* args[] = { (void*)&x, (void*)&wxt, (void*)&bias, (void*)&whtf,
                     (void*)&xp, (void*)&hbuf, (void*)&out, (void*)&bar };
    hipError_t err = hipLaunchCooperativeKernel((const void*)k_mega, dim3(512), dim3(256),
                                                args, 0, stream);
    if (err != hipSuccess) {
        // Plain-launch fallback: capacity (2 blocks/CU x 256 CU) == grid, so
        // all 512 blocks are co-resident regardless of dispatch order.
        k_mega<<<512, 256, 0, stream>>>(x, wxt, bias, whtf, xp, hbuf, out, bar);
    }
}